// Round 7
// baseline (672.880 us; speedup 1.0000x reference)
//
#include <hip/hip_runtime.h>
#include <hip/hip_bf16.h>
#include <math.h>

#define L_    512
#define F_    64
#define M_    (F_*L_)   // 32768
#define D2_   128
#define H_    256
#define LOG2E_ 1.4426950408889634f

typedef unsigned short u16;
typedef __attribute__((ext_vector_type(8))) short s16x8;
typedef __attribute__((ext_vector_type(4))) float f32x4;

__device__ inline u16 bf_hi(float x) {
  union { float f; unsigned u; } v; v.f = x;
  unsigned r = v.u + 0x7fffu + ((v.u >> 16) & 1u);
  return (u16)(r >> 16);
}
__device__ inline float bf_to_f(u16 h) {
  union { float f; unsigned u; } v; v.u = ((unsigned)h) << 16; return v.f;
}
__device__ inline void split2(float x, u16& h, u16& l) {
  h = bf_hi(x);
  l = bf_hi(x - bf_to_f(h));   // exact residual (Sterbenz), bf16-rounded
}
__device__ inline float exp2_fast(float x) {
#if __has_builtin(__builtin_amdgcn_exp2f)
  return __builtin_amdgcn_exp2f(x);
#else
  return __expf(x * 0.6931471805599453f);
#endif
}

// ---------------- geometry: center + covariance + 3x3 eigh ----------------
__global__ void geom_kernel(const float* __restrict__ cords, const float* __restrict__ mask,
                            float* __restrict__ misc) {
  int b = blockIdx.x;
  int t = threadIdx.x;
  __shared__ float red[4][256];
  float sx=0.f, sy=0.f, sz=0.f, sm=0.f;
  for (int l = t; l < 512; l += 256) {
    float m = mask[b*512 + l];
    const float* X = cords + ((size_t)(b*512 + l)*4 + 1)*3;
    sx += X[0]*m; sy += X[1]*m; sz += X[2]*m; sm += m;
  }
  red[0][t]=sx; red[1][t]=sy; red[2][t]=sz; red[3][t]=sm;
  __syncthreads();
  for (int off=128; off>0; off>>=1) {
    if (t < off) { red[0][t]+=red[0][t+off]; red[1][t]+=red[1][t+off];
                   red[2][t]+=red[2][t+off]; red[3][t]+=red[3][t+off]; }
    __syncthreads();
  }
  float inv = 1.f/red[3][0];
  float cx = red[0][0]*inv, cy = red[1][0]*inv, cz = red[2][0]*inv;
  __syncthreads();
  __shared__ float red6[6][256];
  float c00=0,c01=0,c02=0,c11=0,c12=0,c22=0;
  for (int l = t; l < 512; l += 256) {
    float m = mask[b*512+l];
    const float* X = cords + ((size_t)(b*512+l)*4 + 1)*3;
    float x = X[0]-cx*m, y = X[1]-cy*m, z = X[2]-cz*m;
    c00+=x*x; c01+=x*y; c02+=x*z; c11+=y*y; c12+=y*z; c22+=z*z;
  }
  red6[0][t]=c00; red6[1][t]=c01; red6[2][t]=c02;
  red6[3][t]=c11; red6[4][t]=c12; red6[5][t]=c22;
  __syncthreads();
  for (int off=128; off>0; off>>=1) {
    if (t < off) for (int j=0;j<6;j++) red6[j][t]+=red6[j][t+off];
    __syncthreads();
  }
  if (t == 0) {
    double A[3][3], V[3][3];
    A[0][0]=red6[0][0]; A[0][1]=A[1][0]=red6[1][0]; A[0][2]=A[2][0]=red6[2][0];
    A[1][1]=red6[3][0]; A[1][2]=A[2][1]=red6[4][0]; A[2][2]=red6[5][0];
    for (int j=0;j<3;j++) for (int i=0;i<3;i++) V[j][i] = (i==j)?1.0:0.0;
    for (int sweep=0; sweep<10; ++sweep) {
      for (int p=0;p<2;p++) for (int q=p+1;q<3;q++) {
        double apq = A[p][q];
        if (fabs(apq) < 1e-18) continue;
        double app = A[p][p], aqq = A[q][q];
        double tau = (aqq - app) / (2.0*apq);
        double tt = (tau >= 0.0) ? 1.0/(tau + sqrt(1.0+tau*tau))
                                 : 1.0/(tau - sqrt(1.0+tau*tau));
        double cc = 1.0/sqrt(1.0+tt*tt), ss = tt*cc;
        A[p][p] = app - tt*apq;
        A[q][q] = aqq + tt*apq;
        A[p][q] = A[q][p] = 0.0;
        int r = 3 - p - q;
        double arp = A[r][p], arq = A[r][q];
        A[r][p] = A[p][r] = cc*arp - ss*arq;
        A[r][q] = A[q][r] = ss*arp + cc*arq;
        for (int rr2=0; rr2<3; ++rr2) {
          double vrp = V[rr2][p], vrq = V[rr2][q];
          V[rr2][p] = cc*vrp - ss*vrq;
          V[rr2][q] = ss*vrp + cc*vrq;
        }
      }
    }
    double w[3] = {A[0][0], A[1][1], A[2][2]};
    int idx[3] = {0,1,2};
    for (int i=0;i<2;i++) for (int j=0;j<2-i;j++)
      if (w[idx[j]] > w[idx[j+1]]) { int tmp=idx[j]; idx[j]=idx[j+1]; idx[j+1]=tmp; }
    for (int jj=0;jj<3;jj++) for (int ii=0;ii<3;ii++)
      misc[b*12 + jj*3 + ii] = (float)V[jj][idx[ii]];
    misc[b*12+9]=cx; misc[b*12+10]=cy; misc[b*12+11]=cz;
  }
}

// ---------------- build h0 pairs: [F*L][288] = [hX(3) | emb(256) | 0-pad(29)] ----
__global__ void build_h0(const int* __restrict__ seqs, const float* __restrict__ cords,
                         const float* __restrict__ mask, const float* __restrict__ emb,
                         const float* __restrict__ misc,
                         u16* __restrict__ h0h, u16* __restrict__ h0l) {
  int t = threadIdx.x;
  int r = blockIdx.x*4 + (t >> 6);
  int lane = t & 63;
  int f = r >> 9, l = r & 511;
  int b = f >> 3, o = f & 7;
  u16* rh = h0h + (size_t)r * 288;
  u16* rl = h0l + (size_t)r * 288;
  if (lane == 0) {
    float m = mask[b*512 + l];
    const float* X = cords + ((size_t)(b*512 + l)*4 + 1)*3;
    const float* mb = misc + b*12;
    float x = X[0]-mb[9]*m, y = X[1]-mb[10]*m, z = X[2]-mb[11]*m;
    #pragma unroll
    for (int i=0;i<3;i++) {
      float sgn = ((o >> (2-i)) & 1) ? 1.f : -1.f;
      float val = sgn * (mb[0+i]*x + mb[3+i]*y + mb[6+i]*z);
      u16 h,lo; split2(val,h,lo); rh[i]=h; rl[i]=lo;
    }
  }
  if (lane < 29) { rh[259+lane] = 0; rl[259+lane] = 0; }
  int s = seqs[b*512 + l];
  if (s < 0) s = 82;
  const float4 e4 = *((const float4*)(emb + (size_t)s*256) + lane);
  float ev[4] = {e4.x, e4.y, e4.z, e4.w};
  #pragma unroll
  for (int i=0;i<4;i++) {
    u16 h,lo; split2(ev[i],h,lo);
    rh[3 + lane*4 + i] = h; rl[3 + lane*4 + i] = lo;
  }
}

// ---------------- weight prep: transpose + split, zero-pad K ----------------
__global__ void prep_wT(const float* __restrict__ W, u16* __restrict__ Th, u16* __restrict__ Tl,
                        int K, int KP) {
  int n = blockIdx.x;           // 0..127 (output row)
  for (int k = threadIdx.x; k < KP; k += 128) {
    float x = (k < K) ? W[(size_t)k*128 + n] : 0.f;
    u16 h,l; split2(x,h,l);
    Th[(size_t)n*KP + k] = h; Tl[(size_t)n*KP + k] = l;
  }
}

// wuT[(dir*512 + d*4+g)][k] = Wu[k][(dir*4+g)*128 + d]; gates 1,2 pre-scaled by log2(e)
__global__ void prep_wu(const float* __restrict__ Wu, u16* __restrict__ Th, u16* __restrict__ Tl) {
  int n = blockIdx.x;    // 0..511
  int dir = blockIdx.y;  // 0..1
  int k = threadIdx.x;   // 0..127
  int d = n >> 2, g = n & 3;
  float x = Wu[(size_t)k*1024 + (dir*4+g)*128 + d];
  if (g == 1 || g == 2) x *= LOG2E_;
  u16 h,l; split2(x,h,l);
  size_t o = ((size_t)dir*512 + n)*128 + k;
  Th[o]=h; Tl[o]=l;
}

// ---------------- split-bf16 MFMA GEMM ----------------
// C[m][n] = sum_k A[m][k]*B[n][k]  (both operands [row][k] with k-contiguous pairs)
// 128x128 block tile, 4 waves (64x64 each), 16x16x32 bf16 MFMA, 3 MFMAs/frag.
// EPI: 0 = write split pairs Ch/Cl
//      1 = write V^T pairs (transposed per-frame)
//      2 = qkT: scale+mask -> fp32 Cf
//      3 = pv : + residual(rh,rl) -> split pairs
//      4 = write fp32 Cf
template<int EPI>
__global__ __launch_bounds__(256) void gemm_bb(
    const u16* __restrict__ Ah, const u16* __restrict__ Al,
    const u16* __restrict__ Bh, const u16* __restrict__ Bl,
    int KP, int lda, int ldb,
    long aBatch, long bBatch, long cBatch,
    u16* __restrict__ Ch, u16* __restrict__ Cl, int ldc,
    float* __restrict__ Cf,
    const u16* __restrict__ rh, const u16* __restrict__ rl,
    const float* __restrict__ maskp, float scale)
{
  __shared__ u16 As[2][128][40];
  __shared__ u16 Bs[2][128][40];
  const int t = threadIdx.x;
  const int z = blockIdx.z;
  const int bm = blockIdx.x * 128, bn = blockIdx.y * 128;
  Ah += (size_t)z * aBatch; Al += (size_t)z * aBatch;
  Bh += (size_t)z * bBatch; Bl += (size_t)z * bBatch;

  const int lane = t & 63;
  const int w = t >> 6, wr = w >> 1, wc = w & 1;
  const int fr = lane & 15, g = lane >> 4;

  f32x4 acc[4][4] = {};

  for (int k0 = 0; k0 < KP; k0 += 32) {
    #pragma unroll
    for (int cc = 0; cc < 2; cc++) {
      int c = t + cc*256;
      int m = c >> 2, sub = c & 3;
      const size_t ga = (size_t)(bm + m)*lda + k0 + sub*8;
      const size_t gb = (size_t)(bn + m)*ldb + k0 + sub*8;
      *(int4*)&As[0][m][sub*8] = *(const int4*)(Ah + ga);
      *(int4*)&As[1][m][sub*8] = *(const int4*)(Al + ga);
      *(int4*)&Bs[0][m][sub*8] = *(const int4*)(Bh + gb);
      *(int4*)&Bs[1][m][sub*8] = *(const int4*)(Bl + gb);
    }
    __syncthreads();
    s16x8 af[4][2], bfr[4][2];
    #pragma unroll
    for (int i = 0; i < 4; i++) {
      af[i][0]  = *(const s16x8*)&As[0][wr*64 + i*16 + fr][g*8];
      af[i][1]  = *(const s16x8*)&As[1][wr*64 + i*16 + fr][g*8];
      bfr[i][0] = *(const s16x8*)&Bs[0][wc*64 + i*16 + fr][g*8];
      bfr[i][1] = *(const s16x8*)&Bs[1][wc*64 + i*16 + fr][g*8];
    }
    #pragma unroll
    for (int mi = 0; mi < 4; mi++)
      #pragma unroll
      for (int nj = 0; nj < 4; nj++)
        acc[mi][nj] = __builtin_amdgcn_mfma_f32_16x16x32_bf16(af[mi][0], bfr[nj][0], acc[mi][nj], 0,0,0);
    #pragma unroll
    for (int mi = 0; mi < 4; mi++)
      #pragma unroll
      for (int nj = 0; nj < 4; nj++)
        acc[mi][nj] = __builtin_amdgcn_mfma_f32_16x16x32_bf16(af[mi][0], bfr[nj][1], acc[mi][nj], 0,0,0);
    #pragma unroll
    for (int mi = 0; mi < 4; mi++)
      #pragma unroll
      for (int nj = 0; nj < 4; nj++)
        acc[mi][nj] = __builtin_amdgcn_mfma_f32_16x16x32_bf16(af[mi][1], bfr[nj][0], acc[mi][nj], 0,0,0);
    __syncthreads();
  }

  const int rbase = bm + wr*64, nbase = bn + wc*64;
  #pragma unroll
  for (int mi = 0; mi < 4; mi++) {
    #pragma unroll
    for (int nj = 0; nj < 4; nj++) {
      #pragma unroll
      for (int rg = 0; rg < 4; rg++) {
        int r = rbase + mi*16 + g*4 + rg;
        int n = nbase + nj*16 + fr;
        float val = acc[mi][nj][rg];
        if (EPI == 0) {
          size_t o = (size_t)r*ldc + n;
          u16 h,l; split2(val,h,l);
          Ch[o]=h; Cl[o]=l;
        } else if (EPI == 1) {      // V^T pairs: [frame][n][l]
          size_t o = ((size_t)(r >> 9)*128 + n)*512 + (r & 511);
          u16 h,l; split2(val,h,l);
          Ch[o]=h; Cl[o]=l;
        } else if (EPI == 2) {      // qkT -> fp32 S with scale+mask
          float vv = val * scale;
          if (maskp[(z>>3)*512 + n] == 0.f) vv = -1e9f;
          Cf[(size_t)z*cBatch + (size_t)r*ldc + n] = vv;
        } else if (EPI == 3) {      // pv: + q residual -> pairs
          size_t o = (size_t)z*cBatch + (size_t)r*ldc + n;
          float vv = val + (bf_to_f(rh[o]) + bf_to_f(rl[o]));
          u16 h,l; split2(vv,h,l);
          Ch[o]=h; Cl[o]=l;
        } else {                    // 4: fp32 out
          Cf[(size_t)r*ldc + n] = val;
        }
      }
    }
  }
}

// ---------------- row softmax over 512, fp32 in -> split-bf16 pairs in place ----
__global__ void softmax_split(float* __restrict__ S) {
  size_t row = blockIdx.x;
  float* p = S + row*512;
  u16* ph = (u16*)p;        // hi plane: first 1024B of row
  u16* pl = ph + 512;       // lo plane: second 1024B
  int t = threadIdx.x; // 64
  float v[8];
  float mx = -1e30f;
  #pragma unroll
  for (int i=0;i<8;i++) { v[i] = p[t + i*64]; mx = fmaxf(mx, v[i]); }
  #pragma unroll
  for (int off=32; off>0; off>>=1) mx = fmaxf(mx, __shfl_xor(mx, off));
  float sum = 0.f;
  #pragma unroll
  for (int i=0;i<8;i++) { v[i] = __expf(v[i]-mx); sum += v[i]; }
  #pragma unroll
  for (int off=32; off>0; off>>=1) sum += __shfl_xor(sum, off);
  float invs = 1.f/sum;
  #pragma unroll
  for (int i=0;i<8;i++) {
    float x = v[i]*invs;
    u16 h,l; split2(x,h,l);
    ph[t + i*64] = h; pl[t + i*64] = l;
  }
}

// ---------------- sequential SRU scan: inline-asm register pipeline ----------------
// Grid 128 blocks (frame, channel-half), 64 threads (1 wave). 64 chunks ("slots")
// of 8 steps. Loads are asm global_load_dwordx4 with "=v" outputs (compiler cannot
// sink/fold them and inserts NO waitcnt for them); waits are hand-counted
// s_waitcnt vmcnt(N) + sched_barrier(0) (rule #18). 3 rotating buffers = depth-2
// prefetch (~2 slot-times ~640cy cover). Per-slot VMEM stream: 8 loads + 16 h-pair
// stores; N = ops issued after target chunk's loads: 16/32 (prologue), 48 steady,
// 40/32 (epilogue) - all <=63 encodable. Mask values prefetched into registers
// BEFORE the vmcnt wait so lgkm latency hides under it.
#define GLOAD8(buf, ch) do { \
  const int _c = (ch); \
  _Pragma("unroll") \
  for (int s = 0; s < 8; s++) { \
    const int l = (_c*8 + s) ^ lxor; \
    asm volatile("global_load_dwordx4 %0, %1, off" \
      : "=v"(buf[s]) : "v"(Ubase + (size_t)l*512) : "memory"); \
  } \
} while(0)

#define MKRD(ch) do { \
  const int _c = (ch); \
  _Pragma("unroll") \
  for (int s = 0; s < 8; s++) { \
    const int l = (_c*8 + s) ^ lxor; \
    mkb[s] = msk[l]; \
  } \
} while(0)

#define VMWAIT(n) do { \
  asm volatile("s_waitcnt vmcnt(" #n ")" ::: "memory"); \
  __builtin_amdgcn_sched_barrier(0); \
} while(0)

#define COMPC(buf, ch) do { \
  const int _c = (ch); \
  _Pragma("unroll") \
  for (int s = 0; s < 8; s++) { \
    const int l = (_c*8 + s) ^ lxor; \
    const float4 u = buf[s]; \
    const float mkv = mkb[s]; \
    float xf = (u.y + bfd) + vfd*cstate; \
    float xr = (u.z + brd) + vrd*cstate; \
    float fg = 1.f/(1.f + exp2_fast(-xf)); \
    float rg = 1.f/(1.f + exp2_fast(-xr)); \
    float cn = fg*(cstate - u.x) + u.x; \
    if (mkv == 0.f) cn = cstate; \
    float h = (mkv == 0.f) ? 0.f : (rg*(cn - u.w) + u.w); \
    cstate = cn; \
    u16 sh_, sl_; split2(h, sh_, sl_); \
    hpph[(size_t)l*256] = sh_; \
    hppl[(size_t)l*256] = sl_; \
  } \
} while(0)

__global__ __launch_bounds__(64, 1) void sru_scan(const float* __restrict__ U, const float* __restrict__ mask,
                          const float* __restrict__ vf, const float* __restrict__ vr,
                          const float* __restrict__ bf, const float* __restrict__ br,
                          u16* __restrict__ hph, u16* __restrict__ hpl,
                          int dirv) {
  const int blk = blockIdx.x;   // 0..127
  const int f = blk >> 1;       // frame
  const int hh = blk & 1;       // channel half
  const int t = threadIdx.x;    // 0..63
  const int b = f >> 3;
  __shared__ float msk[512];
  for (int i = t; i < 512; i += 64) msk[i] = mask[b*512 + i];
  __syncthreads();
  const int lxor = dirv ? 511 : 0;        // l = step ^ lxor  (511-step == 511^step)
  const int d = hh*64 + t;                // channel within direction
  const float vfd = vf[d]*LOG2E_, vrd = vr[d]*LOG2E_;
  const float bfd = bf[d]*LOG2E_, brd = br[d]*LOG2E_;
  const size_t fbase = (size_t)f * 512;
  const float* Ubase = U + fbase*512 + d*4;
  u16* hpph = hph + fbase*256 + (size_t)dirv*128 + d;
  u16* hppl = hpl + fbase*256 + (size_t)dirv*128 + d;

  float4 bA[8], bB[8], bC[8];
  float mkb[8];
  float cstate = 0.f;

  // prologue: chunks 0,1 in flight
  GLOAD8(bA, 0); GLOAD8(bB, 1);
  // slot 0: after L0 -> L1(8)+L2(8)=16 outstanding
  GLOAD8(bC, 2); MKRD(0); VMWAIT(16); COMPC(bA, 0);
  // slot 1: after L1 -> L2(8)+S0(16)+L3(8)=32
  GLOAD8(bA, 3); MKRD(1); VMWAIT(32); COMPC(bB, 1);
  // slot 2: after L2 -> S0+L3+S1+L4=48
  GLOAD8(bB, 4); MKRD(2); VMWAIT(48); COMPC(bC, 2);
  // steady state: slots 3..59 (19 iterations x 3 slots), N=48
  #pragma unroll 1
  for (int j = 0; j < 19; j++) {
    const int q = 3 + j*3;
    GLOAD8(bC, q+2); MKRD(q);   VMWAIT(48); COMPC(bA, q);
    GLOAD8(bA, q+3); MKRD(q+1); VMWAIT(48); COMPC(bB, q+1);
    GLOAD8(bB, q+4); MKRD(q+2); VMWAIT(48); COMPC(bC, q+2);
  }
  // epilogue: slots 60..63 (chunks 60(A),61(B) computed from loads 60,61 issued in loop)
  GLOAD8(bC, 62); MKRD(60); VMWAIT(48); COMPC(bA, 60);
  GLOAD8(bA, 63); MKRD(61); VMWAIT(48); COMPC(bB, 61);
  // slot 62: after L62 -> S60(16)+L63(8)+S61(16)=40
  MKRD(62); VMWAIT(40); COMPC(bC, 62);
  // slot 63: after L63 -> S61(16)+S62(16)=32
  MKRD(63); VMWAIT(32); COMPC(bA, 63);
}

// ---------------- mean over 8 sign-frames (reads h pairs) ----------------
__global__ void mean_kernel(const u16* __restrict__ hph, const u16* __restrict__ hpl,
                            float* __restrict__ out) {
  int i = blockIdx.x*256 + threadIdx.x;   // 0..131071, 8 channels each
  int row = i >> 5;        // b*512 + l
  int c8  = i & 31;
  int b = row >> 9, l = row & 511;
  float acc[8] = {};
  #pragma unroll
  for (int o=0;o<8;o++) {
    size_t off = ((size_t)((b*8+o)*512 + l))*256 + c8*8;
    union { int4 v; u16 s[8]; } hv, lv;
    hv.v = *(const int4*)(hph + off);
    lv.v = *(const int4*)(hpl + off);
    #pragma unroll
    for (int j=0;j<8;j++)
      acc[j] += bf_to_f(hv.s[j]) + bf_to_f(lv.s[j]);
  }
  float4 r0, r1;
  r0.x=acc[0]*0.125f; r0.y=acc[1]*0.125f; r0.z=acc[2]*0.125f; r0.w=acc[3]*0.125f;
  r1.x=acc[4]*0.125f; r1.y=acc[5]*0.125f; r1.z=acc[6]*0.125f; r1.w=acc[7]*0.125f;
  float* op = out + (size_t)row*256 + c8*8;
  *(float4*)op = r0;
  *(float4*)(op+4) = r1;
}

extern "C" void kernel_launch(void* const* d_in, const int* in_sizes, int n_in,
                              void* d_out, int out_size, void* d_ws, size_t ws_size,
                              hipStream_t stream) {
  const int*   seqs  = (const int*)d_in[0];
  const float* cords = (const float*)d_in[1];
  const float* mask  = (const float*)d_in[2];
  const float* emb   = (const float*)d_in[3];
  const float* Wq[2] = {(const float*)d_in[4],  (const float*)d_in[12]};
  const float* Wk[2] = {(const float*)d_in[5],  (const float*)d_in[13]};
  const float* Wv[2] = {(const float*)d_in[6],  (const float*)d_in[14]};
  const float* Wu[2] = {(const float*)d_in[7],  (const float*)d_in[15]};
  const float* vf[2] = {(const float*)d_in[8],  (const float*)d_in[16]};
  const float* vr[2] = {(const float*)d_in[9],  (const float*)d_in[17]};
  const float* bfp[2]= {(const float*)d_in[10], (const float*)d_in[18]};
  const float* brp[2]= {(const float*)d_in[11], (const float*)d_in[19]};

  char* base = (char*)d_ws;
  float* misc = (float*)base;                                   // 512 B
  u16* h0p_h = (u16*)(base + 512);                              // 2x 32768*288*2 B
  u16* h0p_l = h0p_h + (size_t)M_*288;
  u16* q_h = (u16*)(base + 512 + 2*(size_t)M_*288*2);
  u16* q_l = q_h + (size_t)M_*128;
  u16* k_h = q_l + (size_t)M_*128;
  u16* k_l = k_h + (size_t)M_*128;
  u16* a_h = k_h;  u16* a_l = k_l;                              // overlay (k dead after qkT)
  float* S  = (float*)(k_l + (size_t)M_*128);                   // 64MB: S -> P pairs -> U'
  float* Uprime = S;
  u16* hp_h = (u16*)((char*)S + (size_t)M_*512*4);
  u16* hp_l = hp_h + (size_t)M_*256;
  u16* vT_h = hp_h;  u16* vT_l = hp_l;                          // overlay (vT dead before scan writes hp)
  u16* wqT_h = hp_l + (size_t)M_*256;
  u16* wqT_l = wqT_h + 128*288;
  u16* wkT_h = wqT_l + 128*288;
  u16* wkT_l = wkT_h + 128*128;
  u16* wvT_h = wkT_l + 128*128;
  u16* wvT_l = wvT_h + 128*128;
  u16* wuT_h = wvT_l + 128*128;
  u16* wuT_l = wuT_h + 1024*128;

  geom_kernel<<<8, 256, 0, stream>>>(cords, mask, misc);
  build_h0<<<M_/4, 256, 0, stream>>>(seqs, cords, mask, emb, misc, h0p_h, h0p_l);

  const float scale = 0.08838834764831845f; // 1/sqrt(128)
  for (int layer = 0; layer < 2; ++layer) {
    const u16* Ah_in = layer ? hp_h : h0p_h;
    const u16* Al_in = layer ? hp_l : h0p_l;
    const int  Kq    = layer ? 256 : 259;
    const int  KPq   = layer ? 256 : 288;

    prep_wT<<<128, 128, 0, stream>>>(Wq[layer], wqT_h, wqT_l, Kq, KPq);
    prep_wT<<<128, 128, 0, stream>>>(Wk[layer], wkT_h, wkT_l, 128, 128);
    prep_wT<<<128, 128, 0, stream>>>(Wv[layer], wvT_h, wvT_l, 128, 128);
    prep_wu<<<dim3(512,2), 128, 0, stream>>>(Wu[layer], wuT_h, wuT_l);

    // q = hin @ Wq  -> pairs
    gemm_bb<0><<<dim3(256,1,1), 256, 0, stream>>>(Ah_in, Al_in, wqT_h, wqT_l,
        KPq, KPq, KPq, 0,0,0, q_h, q_l, 128, nullptr, nullptr, nullptr, nullptr, 0.f);
    // k = q @ Wk -> pairs
    gemm_bb<0><<<dim3(256,1,1), 256, 0, stream>>>(q_h, q_l, wkT_h, wkT_l,
        128, 128, 128, 0,0,0, k_h, k_l, 128, nullptr, nullptr, nullptr, nullptr, 0.f);
    // v = q @ Wv -> V^T pairs
    gemm_bb<1><<<dim3(256,1,1), 256, 0, stream>>>(q_h, q_l, wvT_h, wvT_l,
        128, 128, 128, 0,0,0, vT_h, vT_l, 0, nullptr, nullptr, nullptr, nullptr, 0.f);
    // S = q k^T * scale (masked)
    gemm_bb<2><<<dim3(4,4,64), 256, 0, stream>>>(q_h, q_l, k_h, k_l,
        128, 128, 128, 512*128, 512*128, 512*512, nullptr, nullptr, 512, S,
        nullptr, nullptr, mask, scale);
    // P = softmax(S) -> pairs (in place)
    softmax_split<<<M_, 64, 0, stream>>>(S);
    // a = P @ v + q -> pairs
    gemm_bb<3><<<dim3(4,1,64), 256, 0, stream>>>((const u16*)S, (const u16*)S + 512, vT_h, vT_l,
        512, 1024, 512, 512*1024, 128*512, 512*128, a_h, a_l, 128, nullptr,
        q_h, q_l, nullptr, 0.f);
    for (int dir = 0; dir < 2; ++dir) {
      // U' = a @ WuT(dir) -> fp32 (gate-interleaved columns d*4+g; gates 1,2 log2e-scaled)
      gemm_bb<4><<<dim3(256,4,1), 256, 0, stream>>>(a_h, a_l,
          wuT_h + (size_t)dir*512*128, wuT_l + (size_t)dir*512*128,
          128, 128, 128, 0,0,0, nullptr, nullptr, 512, Uprime,
          nullptr, nullptr, nullptr, 0.f);
      sru_scan<<<128, 64, 0, stream>>>(Uprime, mask, vf[layer]+dir*128, vr[layer]+dir*128,
                                       bfp[layer]+dir*128, brp[layer]+dir*128,
                                       hp_h, hp_l, dir);
    }
  }
  mean_kernel<<<512, 256, 0, stream>>>(hp_h, hp_l, (float*)d_out);
}

// Round 8
// 668.916 us; speedup vs baseline: 1.0059x; 1.0059x over previous
//
#include <hip/hip_runtime.h>
#include <hip/hip_bf16.h>
#include <math.h>

#define L_    512
#define F_    64
#define M_    (F_*L_)   // 32768
#define D2_   128
#define H_    256
#define LOG2E_ 1.4426950408889634f

typedef unsigned short u16;
typedef __attribute__((ext_vector_type(8))) short s16x8;
typedef __attribute__((ext_vector_type(4))) float f32x4;

__device__ inline u16 bf_hi(float x) {
  union { float f; unsigned u; } v; v.f = x;
  unsigned r = v.u + 0x7fffu + ((v.u >> 16) & 1u);
  return (u16)(r >> 16);
}
__device__ inline float bf_to_f(u16 h) {
  union { float f; unsigned u; } v; v.u = ((unsigned)h) << 16; return v.f;
}
__device__ inline void split2(float x, u16& h, u16& l) {
  h = bf_hi(x);
  l = bf_hi(x - bf_to_f(h));   // exact residual (Sterbenz), bf16-rounded
}
__device__ inline float exp2_fast(float x) {
#if __has_builtin(__builtin_amdgcn_exp2f)
  return __builtin_amdgcn_exp2f(x);
#else
  return __expf(x * 0.6931471805599453f);
#endif
}

// ---------------- geometry: center + covariance + 3x3 eigh ----------------
__global__ void geom_kernel(const float* __restrict__ cords, const float* __restrict__ mask,
                            float* __restrict__ misc) {
  int b = blockIdx.x;
  int t = threadIdx.x;
  __shared__ float red[4][256];
  float sx=0.f, sy=0.f, sz=0.f, sm=0.f;
  for (int l = t; l < 512; l += 256) {
    float m = mask[b*512 + l];
    const float* X = cords + ((size_t)(b*512 + l)*4 + 1)*3;
    sx += X[0]*m; sy += X[1]*m; sz += X[2]*m; sm += m;
  }
  red[0][t]=sx; red[1][t]=sy; red[2][t]=sz; red[3][t]=sm;
  __syncthreads();
  for (int off=128; off>0; off>>=1) {
    if (t < off) { red[0][t]+=red[0][t+off]; red[1][t]+=red[1][t+off];
                   red[2][t]+=red[2][t+off]; red[3][t]+=red[3][t+off]; }
    __syncthreads();
  }
  float inv = 1.f/red[3][0];
  float cx = red[0][0]*inv, cy = red[1][0]*inv, cz = red[2][0]*inv;
  __syncthreads();
  __shared__ float red6[6][256];
  float c00=0,c01=0,c02=0,c11=0,c12=0,c22=0;
  for (int l = t; l < 512; l += 256) {
    float m = mask[b*512+l];
    const float* X = cords + ((size_t)(b*512+l)*4 + 1)*3;
    float x = X[0]-cx*m, y = X[1]-cy*m, z = X[2]-cz*m;
    c00+=x*x; c01+=x*y; c02+=x*z; c11+=y*y; c12+=y*z; c22+=z*z;
  }
  red6[0][t]=c00; red6[1][t]=c01; red6[2][t]=c02;
  red6[3][t]=c11; red6[4][t]=c12; red6[5][t]=c22;
  __syncthreads();
  for (int off=128; off>0; off>>=1) {
    if (t < off) for (int j=0;j<6;j++) red6[j][t]+=red6[j][t+off];
    __syncthreads();
  }
  if (t == 0) {
    double A[3][3], V[3][3];
    A[0][0]=red6[0][0]; A[0][1]=A[1][0]=red6[1][0]; A[0][2]=A[2][0]=red6[2][0];
    A[1][1]=red6[3][0]; A[1][2]=A[2][1]=red6[4][0]; A[2][2]=red6[5][0];
    for (int j=0;j<3;j++) for (int i=0;i<3;i++) V[j][i] = (i==j)?1.0:0.0;
    for (int sweep=0; sweep<10; ++sweep) {
      for (int p=0;p<2;p++) for (int q=p+1;q<3;q++) {
        double apq = A[p][q];
        if (fabs(apq) < 1e-18) continue;
        double app = A[p][p], aqq = A[q][q];
        double tau = (aqq - app) / (2.0*apq);
        double tt = (tau >= 0.0) ? 1.0/(tau + sqrt(1.0+tau*tau))
                                 : 1.0/(tau - sqrt(1.0+tau*tau));
        double cc = 1.0/sqrt(1.0+tt*tt), ss = tt*cc;
        A[p][p] = app - tt*apq;
        A[q][q] = aqq + tt*apq;
        A[p][q] = A[q][p] = 0.0;
        int r = 3 - p - q;
        double arp = A[r][p], arq = A[r][q];
        A[r][p] = A[p][r] = cc*arp - ss*arq;
        A[r][q] = A[q][r] = ss*arp + cc*arq;
        for (int rr2=0; rr2<3; ++rr2) {
          double vrp = V[rr2][p], vrq = V[rr2][q];
          V[rr2][p] = cc*vrp - ss*vrq;
          V[rr2][q] = ss*vrp + cc*vrq;
        }
      }
    }
    double w[3] = {A[0][0], A[1][1], A[2][2]};
    int idx[3] = {0,1,2};
    for (int i=0;i<2;i++) for (int j=0;j<2-i;j++)
      if (w[idx[j]] > w[idx[j+1]]) { int tmp=idx[j]; idx[j]=idx[j+1]; idx[j+1]=tmp; }
    for (int jj=0;jj<3;jj++) for (int ii=0;ii<3;ii++)
      misc[b*12 + jj*3 + ii] = (float)V[jj][idx[ii]];
    misc[b*12+9]=cx; misc[b*12+10]=cy; misc[b*12+11]=cz;
  }
}

// ---------------- build h0 pairs: [F*L][288] = [hX(3) | emb(256) | 0-pad(29)] ----
__global__ void build_h0(const int* __restrict__ seqs, const float* __restrict__ cords,
                         const float* __restrict__ mask, const float* __restrict__ emb,
                         const float* __restrict__ misc,
                         u16* __restrict__ h0h, u16* __restrict__ h0l) {
  int t = threadIdx.x;
  int r = blockIdx.x*4 + (t >> 6);
  int lane = t & 63;
  int f = r >> 9, l = r & 511;
  int b = f >> 3, o = f & 7;
  u16* rh = h0h + (size_t)r * 288;
  u16* rl = h0l + (size_t)r * 288;
  if (lane == 0) {
    float m = mask[b*512 + l];
    const float* X = cords + ((size_t)(b*512 + l)*4 + 1)*3;
    const float* mb = misc + b*12;
    float x = X[0]-mb[9]*m, y = X[1]-mb[10]*m, z = X[2]-mb[11]*m;
    #pragma unroll
    for (int i=0;i<3;i++) {
      float sgn = ((o >> (2-i)) & 1) ? 1.f : -1.f;
      float val = sgn * (mb[0+i]*x + mb[3+i]*y + mb[6+i]*z);
      u16 h,lo; split2(val,h,lo); rh[i]=h; rl[i]=lo;
    }
  }
  if (lane < 29) { rh[259+lane] = 0; rl[259+lane] = 0; }
  int s = seqs[b*512 + l];
  if (s < 0) s = 82;
  const float4 e4 = *((const float4*)(emb + (size_t)s*256) + lane);
  float ev[4] = {e4.x, e4.y, e4.z, e4.w};
  #pragma unroll
  for (int i=0;i<4;i++) {
    u16 h,lo; split2(ev[i],h,lo);
    rh[3 + lane*4 + i] = h; rl[3 + lane*4 + i] = lo;
  }
}

// ---------------- weight prep: transpose + split, zero-pad K ----------------
__global__ void prep_wT(const float* __restrict__ W, u16* __restrict__ Th, u16* __restrict__ Tl,
                        int K, int KP) {
  int n = blockIdx.x;           // 0..127 (output row)
  for (int k = threadIdx.x; k < KP; k += 128) {
    float x = (k < K) ? W[(size_t)k*128 + n] : 0.f;
    u16 h,l; split2(x,h,l);
    Th[(size_t)n*KP + k] = h; Tl[(size_t)n*KP + k] = l;
  }
}

// wuT[(dir*512 + d*4+g)][k] = Wu[k][(dir*4+g)*128 + d]; gates 1,2 pre-scaled by log2(e)
__global__ void prep_wu(const float* __restrict__ Wu, u16* __restrict__ Th, u16* __restrict__ Tl) {
  int n = blockIdx.x;    // 0..511
  int dir = blockIdx.y;  // 0..1
  int k = threadIdx.x;   // 0..127
  int d = n >> 2, g = n & 3;
  float x = Wu[(size_t)k*1024 + (dir*4+g)*128 + d];
  if (g == 1 || g == 2) x *= LOG2E_;
  u16 h,l; split2(x,h,l);
  size_t o = ((size_t)dir*512 + n)*128 + k;
  Th[o]=h; Tl[o]=l;
}

// ---------------- split-bf16 MFMA GEMM ----------------
template<int EPI>
__global__ __launch_bounds__(256) void gemm_bb(
    const u16* __restrict__ Ah, const u16* __restrict__ Al,
    const u16* __restrict__ Bh, const u16* __restrict__ Bl,
    int KP, int lda, int ldb,
    long aBatch, long bBatch, long cBatch,
    u16* __restrict__ Ch, u16* __restrict__ Cl, int ldc,
    float* __restrict__ Cf,
    const u16* __restrict__ rh, const u16* __restrict__ rl,
    const float* __restrict__ maskp, float scale)
{
  __shared__ u16 As[2][128][40];
  __shared__ u16 Bs[2][128][40];
  const int t = threadIdx.x;
  const int z = blockIdx.z;
  const int bm = blockIdx.x * 128, bn = blockIdx.y * 128;
  Ah += (size_t)z * aBatch; Al += (size_t)z * aBatch;
  Bh += (size_t)z * bBatch; Bl += (size_t)z * bBatch;

  const int lane = t & 63;
  const int w = t >> 6, wr = w >> 1, wc = w & 1;
  const int fr = lane & 15, g = lane >> 4;

  f32x4 acc[4][4] = {};

  for (int k0 = 0; k0 < KP; k0 += 32) {
    #pragma unroll
    for (int cc = 0; cc < 2; cc++) {
      int c = t + cc*256;
      int m = c >> 2, sub = c & 3;
      const size_t ga = (size_t)(bm + m)*lda + k0 + sub*8;
      const size_t gb = (size_t)(bn + m)*ldb + k0 + sub*8;
      *(int4*)&As[0][m][sub*8] = *(const int4*)(Ah + ga);
      *(int4*)&As[1][m][sub*8] = *(const int4*)(Al + ga);
      *(int4*)&Bs[0][m][sub*8] = *(const int4*)(Bh + gb);
      *(int4*)&Bs[1][m][sub*8] = *(const int4*)(Bl + gb);
    }
    __syncthreads();
    s16x8 af[4][2], bfr[4][2];
    #pragma unroll
    for (int i = 0; i < 4; i++) {
      af[i][0]  = *(const s16x8*)&As[0][wr*64 + i*16 + fr][g*8];
      af[i][1]  = *(const s16x8*)&As[1][wr*64 + i*16 + fr][g*8];
      bfr[i][0] = *(const s16x8*)&Bs[0][wc*64 + i*16 + fr][g*8];
      bfr[i][1] = *(const s16x8*)&Bs[1][wc*64 + i*16 + fr][g*8];
    }
    #pragma unroll
    for (int mi = 0; mi < 4; mi++)
      #pragma unroll
      for (int nj = 0; nj < 4; nj++)
        acc[mi][nj] = __builtin_amdgcn_mfma_f32_16x16x32_bf16(af[mi][0], bfr[nj][0], acc[mi][nj], 0,0,0);
    #pragma unroll
    for (int mi = 0; mi < 4; mi++)
      #pragma unroll
      for (int nj = 0; nj < 4; nj++)
        acc[mi][nj] = __builtin_amdgcn_mfma_f32_16x16x32_bf16(af[mi][0], bfr[nj][1], acc[mi][nj], 0,0,0);
    #pragma unroll
    for (int mi = 0; mi < 4; mi++)
      #pragma unroll
      for (int nj = 0; nj < 4; nj++)
        acc[mi][nj] = __builtin_amdgcn_mfma_f32_16x16x32_bf16(af[mi][1], bfr[nj][0], acc[mi][nj], 0,0,0);
    __syncthreads();
  }

  const int rbase = bm + wr*64, nbase = bn + wc*64;
  #pragma unroll
  for (int mi = 0; mi < 4; mi++) {
    #pragma unroll
    for (int nj = 0; nj < 4; nj++) {
      #pragma unroll
      for (int rg = 0; rg < 4; rg++) {
        int r = rbase + mi*16 + g*4 + rg;
        int n = nbase + nj*16 + fr;
        float val = acc[mi][nj][rg];
        if (EPI == 0) {
          size_t o = (size_t)r*ldc + n;
          u16 h,l; split2(val,h,l);
          Ch[o]=h; Cl[o]=l;
        } else if (EPI == 1) {      // V^T pairs: [frame][n][l]
          size_t o = ((size_t)(r >> 9)*128 + n)*512 + (r & 511);
          u16 h,l; split2(val,h,l);
          Ch[o]=h; Cl[o]=l;
        } else if (EPI == 2) {      // qkT -> fp32 S with scale+mask
          float vv = val * scale;
          if (maskp[(z>>3)*512 + n] == 0.f) vv = -1e9f;
          Cf[(size_t)z*cBatch + (size_t)r*ldc + n] = vv;
        } else if (EPI == 3) {      // pv: + q residual -> pairs
          size_t o = (size_t)z*cBatch + (size_t)r*ldc + n;
          float vv = val + (bf_to_f(rh[o]) + bf_to_f(rl[o]));
          u16 h,l; split2(vv,h,l);
          Ch[o]=h; Cl[o]=l;
        } else {                    // 4: fp32 out
          Cf[(size_t)r*ldc + n] = val;
        }
      }
    }
  }
}

// ---------------- row softmax over 512, fp32 in -> split-bf16 pairs in place ----
__global__ void softmax_split(float* __restrict__ S) {
  size_t row = blockIdx.x;
  float* p = S + row*512;
  u16* ph = (u16*)p;        // hi plane: first 1024B of row
  u16* pl = ph + 512;       // lo plane: second 1024B
  int t = threadIdx.x; // 64
  float v[8];
  float mx = -1e30f;
  #pragma unroll
  for (int i=0;i<8;i++) { v[i] = p[t + i*64]; mx = fmaxf(mx, v[i]); }
  #pragma unroll
  for (int off=32; off>0; off>>=1) mx = fmaxf(mx, __shfl_xor(mx, off));
  float sum = 0.f;
  #pragma unroll
  for (int i=0;i<8;i++) { v[i] = __expf(v[i]-mx); sum += v[i]; }
  #pragma unroll
  for (int off=32; off>0; off>>=1) sum += __shfl_xor(sum, off);
  float invs = 1.f/sum;
  #pragma unroll
  for (int i=0;i<8;i++) {
    float x = v[i]*invs;
    u16 h,l; split2(x,h,l);
    ph[t + i*64] = h; pl[t + i*64] = l;
  }
}

// ---------------- SRU scan: producer/consumer waves ----------------
// 128 blocks (frame, channel-half) x 128 threads (2 waves).
// Wave0 = producer: pure-load vmcnt FIFO (no stores ever -> counted waits are
// exact, no store-ack pollution, no 63-entry cap pressure). Depth-4 register
// pipeline (32 loads = 32KB/wave in flight), inline-asm loads (compiler cannot
// sink), VMWAIT(24) confirms chunk q+1, then LDS-commit it.
// Wave1 = consumer: ds_read (lgkm counter, disjoint from store acks) + gate
// chain + h-pair stores that are NEVER waited on.
// Sync: raw s_barrier (NOT __syncthreads, which drains vmcnt and would kill the
// prefetch queue) + asm memory fences. 3 LDS chunk buffers, 1 barrier/slot.
#define VMWAIT(n) do { \
  asm volatile("s_waitcnt vmcnt(" #n ")" ::: "memory"); \
  __builtin_amdgcn_sched_barrier(0); \
} while(0)

#define BARRIER() do { \
  asm volatile("" ::: "memory"); \
  __builtin_amdgcn_s_barrier(); \
  asm volatile("" ::: "memory"); \
} while(0)

#define PGLOAD(REG, ch) do { \
  const int _c = (ch); \
  _Pragma("unroll") \
  for (int s = 0; s < 8; s++) { \
    const int l = (_c*8 + s) ^ lxor; \
    asm volatile("global_load_dwordx4 %0, %1, off" \
      : "=v"(REG[s]) : "v"(Pbase + (size_t)l*512) : "memory"); \
  } \
} while(0)

#define PDSW(REG, bwv) do { \
  float* _dst = &bufs[(bwv)*2048 + lane*4]; \
  _Pragma("unroll") \
  for (int s = 0; s < 8; s++) \
    *(float4*)(_dst + s*256) = REG[s]; \
  asm volatile("s_waitcnt lgkmcnt(0)" ::: "memory"); \
} while(0)

#define CSLOT(qv, brv) do { \
  const float* _b = &bufs[(brv)*2048 + lane*4]; \
  float4 uu[8]; \
  _Pragma("unroll") \
  for (int s = 0; s < 8; s++) uu[s] = *(const float4*)(_b + s*256); \
  _Pragma("unroll") \
  for (int s = 0; s < 8; s++) { \
    const int l = ((qv)*8 + s) ^ lxor; \
    const float4 u = uu[s]; \
    const float mkv = msk[l]; \
    float xf = (u.y + bfd) + vfd*cstate; \
    float xr = (u.z + brd) + vrd*cstate; \
    float fg = 1.f/(1.f + exp2_fast(-xf)); \
    float rg = 1.f/(1.f + exp2_fast(-xr)); \
    float cn = fg*(cstate - u.x) + u.x; \
    if (mkv == 0.f) cn = cstate; \
    float h = (mkv == 0.f) ? 0.f : (rg*(cn - u.w) + u.w); \
    cstate = cn; \
    u16 sh_, sl_; split2(h, sh_, sl_); \
    hpph[(size_t)l*256] = sh_; \
    hppl[(size_t)l*256] = sl_; \
  } \
} while(0)

#define BUMP() do { br_ = (br_==2)?0:br_+1; bw_ = (bw_==2)?0:bw_+1; } while(0)

__global__ __launch_bounds__(128, 1) void sru_scan(const float* __restrict__ U, const float* __restrict__ mask,
                          const float* __restrict__ vf, const float* __restrict__ vr,
                          const float* __restrict__ bf, const float* __restrict__ br,
                          u16* __restrict__ hph, u16* __restrict__ hpl,
                          int dirv) {
  const int blk = blockIdx.x;   // 0..127
  const int f = blk >> 1;       // frame
  const int hh = blk & 1;       // channel half
  const int t = threadIdx.x;    // 0..127
  const int wid = t >> 6, lane = t & 63;
  const int b = f >> 3;
  __shared__ __align__(16) float bufs[3*2048];   // 3 chunk buffers, 8KB each
  __shared__ float msk[512];
  for (int i = t; i < 512; i += 128) msk[i] = mask[b*512 + i];
  __syncthreads();   // safe: nothing in flight yet

  const int lxor = dirv ? 511 : 0;        // l = step ^ lxor
  const size_t fbase = (size_t)f * 512;
  // consumer-side params
  const int d = hh*64 + lane;
  const float vfd = vf[d]*LOG2E_, vrd = vr[d]*LOG2E_;
  const float bfd = bf[d]*LOG2E_, brd = br[d]*LOG2E_;
  u16* hpph = hph + fbase*256 + (size_t)dirv*128 + d;
  u16* hppl = hpl + fbase*256 + (size_t)dirv*128 + d;
  float cstate = 0.f;
  // producer-side per-lane global base: step l row, our 256-col half, lane*4 floats
  const float* Pbase = U + fbase*512 + hh*256 + lane*4;

  float4 r0[8], r1[8], r2[8], r3[8];
  if (wid == 0) {
    PGLOAD(r0, 0); PGLOAD(r1, 1); PGLOAD(r2, 2); PGLOAD(r3, 3);
    VMWAIT(24);          // chunk 0 arrived
    PDSW(r0, 0);         // commit chunk 0 -> buf0
  }
  int br_ = 0, bw_ = 1;
  #pragma unroll 1
  for (int j = 0; j < 15; j++) {
    const int q = j*4;   // slots q .. q+3
    BARRIER();
    if (wid == 0) { PGLOAD(r0, q+4); VMWAIT(24); PDSW(r1, bw_); }
    else          CSLOT(q, br_);
    BUMP();
    BARRIER();
    if (wid == 0) { PGLOAD(r1, q+5); VMWAIT(24); PDSW(r2, bw_); }
    else          CSLOT(q+1, br_);
    BUMP();
    BARRIER();
    if (wid == 0) { PGLOAD(r2, q+6); VMWAIT(24); PDSW(r3, bw_); }
    else          CSLOT(q+2, br_);
    BUMP();
    BARRIER();
    if (wid == 0) { PGLOAD(r3, q+7); VMWAIT(24); PDSW(r0, bw_); }
    else          CSLOT(q+3, br_);
    BUMP();
  }
  // tail slots 60..63 (chunks 60..63 already loaded into r0..r3)
  BARRIER();
  if (wid == 0) { VMWAIT(16); PDSW(r1, bw_); }   // commit chunk 61
  else          CSLOT(60, br_);
  BUMP();
  BARRIER();
  if (wid == 0) { VMWAIT(8);  PDSW(r2, bw_); }   // commit chunk 62
  else          CSLOT(61, br_);
  BUMP();
  BARRIER();
  if (wid == 0) { VMWAIT(0);  PDSW(r3, bw_); }   // commit chunk 63
  else          CSLOT(62, br_);
  BUMP();
  BARRIER();
  if (wid != 0) CSLOT(63, br_);
}

// ---------------- mean over 8 sign-frames (reads h pairs) ----------------
__global__ void mean_kernel(const u16* __restrict__ hph, const u16* __restrict__ hpl,
                            float* __restrict__ out) {
  int i = blockIdx.x*256 + threadIdx.x;   // 0..131071, 8 channels each
  int row = i >> 5;        // b*512 + l
  int c8  = i & 31;
  int b = row >> 9, l = row & 511;
  float acc[8] = {};
  #pragma unroll
  for (int o=0;o<8;o++) {
    size_t off = ((size_t)((b*8+o)*512 + l))*256 + c8*8;
    union { int4 v; u16 s[8]; } hv, lv;
    hv.v = *(const int4*)(hph + off);
    lv.v = *(const int4*)(hpl + off);
    #pragma unroll
    for (int j=0;j<8;j++)
      acc[j] += bf_to_f(hv.s[j]) + bf_to_f(lv.s[j]);
  }
  float4 q0, q1;
  q0.x=acc[0]*0.125f; q0.y=acc[1]*0.125f; q0.z=acc[2]*0.125f; q0.w=acc[3]*0.125f;
  q1.x=acc[4]*0.125f; q1.y=acc[5]*0.125f; q1.z=acc[6]*0.125f; q1.w=acc[7]*0.125f;
  float* op = out + (size_t)row*256 + c8*8;
  *(float4*)op = q0;
  *(float4*)(op+4) = q1;
}

extern "C" void kernel_launch(void* const* d_in, const int* in_sizes, int n_in,
                              void* d_out, int out_size, void* d_ws, size_t ws_size,
                              hipStream_t stream) {
  const int*   seqs  = (const int*)d_in[0];
  const float* cords = (const float*)d_in[1];
  const float* mask  = (const float*)d_in[2];
  const float* emb   = (const float*)d_in[3];
  const float* Wq[2] = {(const float*)d_in[4],  (const float*)d_in[12]};
  const float* Wk[2] = {(const float*)d_in[5],  (const float*)d_in[13]};
  const float* Wv[2] = {(const float*)d_in[6],  (const float*)d_in[14]};
  const float* Wu[2] = {(const float*)d_in[7],  (const float*)d_in[15]};
  const float* vf[2] = {(const float*)d_in[8],  (const float*)d_in[16]};
  const float* vr[2] = {(const float*)d_in[9],  (const float*)d_in[17]};
  const float* bfp[2]= {(const float*)d_in[10], (const float*)d_in[18]};
  const float* brp[2]= {(const float*)d_in[11], (const float*)d_in[19]};

  char* base = (char*)d_ws;
  float* misc = (float*)base;                                   // 512 B
  u16* h0p_h = (u16*)(base + 512);                              // 2x 32768*288*2 B
  u16* h0p_l = h0p_h + (size_t)M_*288;
  u16* q_h = (u16*)(base + 512 + 2*(size_t)M_*288*2);
  u16* q_l = q_h + (size_t)M_*128;
  u16* k_h = q_l + (size_t)M_*128;
  u16* k_l = k_h + (size_t)M_*128;
  u16* a_h = k_h;  u16* a_l = k_l;                              // overlay (k dead after qkT)
  float* S  = (float*)(k_l + (size_t)M_*128);                   // 64MB: S -> P pairs -> U'
  float* Uprime = S;
  u16* hp_h = (u16*)((char*)S + (size_t)M_*512*4);
  u16* hp_l = hp_h + (size_t)M_*256;
  u16* vT_h = hp_h;  u16* vT_l = hp_l;                          // overlay (vT dead before scan writes hp)
  u16* wqT_h = hp_l + (size_t)M_*256;
  u16* wqT_l = wqT_h + 128*288;
  u16* wkT_h = wqT_l + 128*288;
  u16* wkT_l = wkT_h + 128*128;
  u16* wvT_h = wkT_l + 128*128;
  u16* wvT_l = wvT_h + 128*128;
  u16* wuT_h = wvT_l + 128*128;
  u16* wuT_l = wuT_h + 1024*128;

  geom_kernel<<<8, 256, 0, stream>>>(cords, mask, misc);
  build_h0<<<M_/4, 256, 0, stream>>>(seqs, cords, mask, emb, misc, h0p_h, h0p_l);

  const float scale = 0.08838834764831845f; // 1/sqrt(128)
  for (int layer = 0; layer < 2; ++layer) {
    const u16* Ah_in = layer ? hp_h : h0p_h;
    const u16* Al_in = layer ? hp_l : h0p_l;
    const int  Kq    = layer ? 256 : 259;
    const int  KPq   = layer ? 256 : 288;

    prep_wT<<<128, 128, 0, stream>>>(Wq[layer], wqT_h, wqT_l, Kq, KPq);
    prep_wT<<<128, 128, 0, stream>>>(Wk[layer], wkT_h, wkT_l, 128, 128);
    prep_wT<<<128, 128, 0, stream>>>(Wv[layer], wvT_h, wvT_l, 128, 128);
    prep_wu<<<dim3(512,2), 128, 0, stream>>>(Wu[layer], wuT_h, wuT_l);

    // q = hin @ Wq  -> pairs
    gemm_bb<0><<<dim3(256,1,1), 256, 0, stream>>>(Ah_in, Al_in, wqT_h, wqT_l,
        KPq, KPq, KPq, 0,0,0, q_h, q_l, 128, nullptr, nullptr, nullptr, nullptr, 0.f);
    // k = q @ Wk -> pairs
    gemm_bb<0><<<dim3(256,1,1), 256, 0, stream>>>(q_h, q_l, wkT_h, wkT_l,
        128, 128, 128, 0,0,0, k_h, k_l, 128, nullptr, nullptr, nullptr, nullptr, 0.f);
    // v = q @ Wv -> V^T pairs
    gemm_bb<1><<<dim3(256,1,1), 256, 0, stream>>>(q_h, q_l, wvT_h, wvT_l,
        128, 128, 128, 0,0,0, vT_h, vT_l, 0, nullptr, nullptr, nullptr, nullptr, 0.f);
    // S = q k^T * scale (masked)
    gemm_bb<2><<<dim3(4,4,64), 256, 0, stream>>>(q_h, q_l, k_h, k_l,
        128, 128, 128, 512*128, 512*128, 512*512, nullptr, nullptr, 512, S,
        nullptr, nullptr, mask, scale);
    // P = softmax(S) -> pairs (in place)
    softmax_split<<<M_, 64, 0, stream>>>(S);
    // a = P @ v + q -> pairs
    gemm_bb<3><<<dim3(4,1,64), 256, 0, stream>>>((const u16*)S, (const u16*)S + 512, vT_h, vT_l,
        512, 1024, 512, 512*1024, 128*512, 512*128, a_h, a_l, 128, nullptr,
        q_h, q_l, nullptr, 0.f);
    for (int dir = 0; dir < 2; ++dir) {
      // U' = a @ WuT(dir) -> fp32 (gate-interleaved columns d*4+g; gates 1,2 log2e-scaled)
      gemm_bb<4><<<dim3(256,4,1), 256, 0, stream>>>(a_h, a_l,
          wuT_h + (size_t)dir*512*128, wuT_l + (size_t)dir*512*128,
          128, 128, 128, 0,0,0, nullptr, nullptr, 512, Uprime,
          nullptr, nullptr, nullptr, 0.f);
      sru_scan<<<128, 128, 0, stream>>>(Uprime, mask, vf[layer]+dir*128, vr[layer]+dir*128,
                                        bfp[layer]+dir*128, brp[layer]+dir*128,
                                        hp_h, hp_l, dir);
    }
  }
  mean_kernel<<<512, 256, 0, stream>>>(hp_h, hp_l, (float*)d_out);
}

// Round 9
// 538.968 us; speedup vs baseline: 1.2485x; 1.2411x over previous
//
#include <hip/hip_runtime.h>
#include <hip/hip_bf16.h>
#include <math.h>

#define L_    512
#define F_    64
#define M_    (F_*L_)   // 32768
#define D2_   128
#define H_    256
#define LOG2E_ 1.4426950408889634f

typedef unsigned short u16;
typedef __attribute__((ext_vector_type(8))) short s16x8;
typedef __attribute__((ext_vector_type(4))) float f32x4;

__device__ inline u16 bf_hi(float x) {
  union { float f; unsigned u; } v; v.f = x;
  unsigned r = v.u + 0x7fffu + ((v.u >> 16) & 1u);
  return (u16)(r >> 16);
}
__device__ inline float bf_to_f(u16 h) {
  union { float f; unsigned u; } v; v.u = ((unsigned)h) << 16; return v.f;
}
__device__ inline void split2(float x, u16& h, u16& l) {
  h = bf_hi(x);
  l = bf_hi(x - bf_to_f(h));   // exact residual (Sterbenz), bf16-rounded
}
__device__ inline float exp2_fast(float x) {
#if __has_builtin(__builtin_amdgcn_exp2f)
  return __builtin_amdgcn_exp2f(x);
#else
  return __expf(x * 0.6931471805599453f);
#endif
}

// U'1 row-split thresholds (rows of 512 fp32). Frame-aligned: 36*512, 52*512.
#define RSPLIT_A 18432
#define RSPLIT_B 26624

// ---------------- geometry: center + covariance + 3x3 eigh ----------------
__global__ void geom_kernel(const float* __restrict__ cords, const float* __restrict__ mask,
                            float* __restrict__ misc) {
  int b = blockIdx.x;
  int t = threadIdx.x;
  __shared__ float red[4][256];
  float sx=0.f, sy=0.f, sz=0.f, sm=0.f;
  for (int l = t; l < 512; l += 256) {
    float m = mask[b*512 + l];
    const float* X = cords + ((size_t)(b*512 + l)*4 + 1)*3;
    sx += X[0]*m; sy += X[1]*m; sz += X[2]*m; sm += m;
  }
  red[0][t]=sx; red[1][t]=sy; red[2][t]=sz; red[3][t]=sm;
  __syncthreads();
  for (int off=128; off>0; off>>=1) {
    if (t < off) { red[0][t]+=red[0][t+off]; red[1][t]+=red[1][t+off];
                   red[2][t]+=red[2][t+off]; red[3][t]+=red[3][t+off]; }
    __syncthreads();
  }
  float inv = 1.f/red[3][0];
  float cx = red[0][0]*inv, cy = red[1][0]*inv, cz = red[2][0]*inv;
  __syncthreads();
  __shared__ float red6[6][256];
  float c00=0,c01=0,c02=0,c11=0,c12=0,c22=0;
  for (int l = t; l < 512; l += 256) {
    float m = mask[b*512+l];
    const float* X = cords + ((size_t)(b*512+l)*4 + 1)*3;
    float x = X[0]-cx*m, y = X[1]-cy*m, z = X[2]-cz*m;
    c00+=x*x; c01+=x*y; c02+=x*z; c11+=y*y; c12+=y*z; c22+=z*z;
  }
  red6[0][t]=c00; red6[1][t]=c01; red6[2][t]=c02;
  red6[3][t]=c11; red6[4][t]=c12; red6[5][t]=c22;
  __syncthreads();
  for (int off=128; off>0; off>>=1) {
    if (t < off) for (int j=0;j<6;j++) red6[j][t]+=red6[j][t+off];
    __syncthreads();
  }
  if (t == 0) {
    double A[3][3], V[3][3];
    A[0][0]=red6[0][0]; A[0][1]=A[1][0]=red6[1][0]; A[0][2]=A[2][0]=red6[2][0];
    A[1][1]=red6[3][0]; A[1][2]=A[2][1]=red6[4][0]; A[2][2]=red6[5][0];
    for (int j=0;j<3;j++) for (int i=0;i<3;i++) V[j][i] = (i==j)?1.0:0.0;
    for (int sweep=0; sweep<10; ++sweep) {
      for (int p=0;p<2;p++) for (int q=p+1;q<3;q++) {
        double apq = A[p][q];
        if (fabs(apq) < 1e-18) continue;
        double app = A[p][p], aqq = A[q][q];
        double tau = (aqq - app) / (2.0*apq);
        double tt = (tau >= 0.0) ? 1.0/(tau + sqrt(1.0+tau*tau))
                                 : 1.0/(tau - sqrt(1.0+tau*tau));
        double cc = 1.0/sqrt(1.0+tt*tt), ss = tt*cc;
        A[p][p] = app - tt*apq;
        A[q][q] = aqq + tt*apq;
        A[p][q] = A[q][p] = 0.0;
        int r = 3 - p - q;
        double arp = A[r][p], arq = A[r][q];
        A[r][p] = A[p][r] = cc*arp - ss*arq;
        A[r][q] = A[q][r] = ss*arp + cc*arq;
        for (int rr2=0; rr2<3; ++rr2) {
          double vrp = V[rr2][p], vrq = V[rr2][q];
          V[rr2][p] = cc*vrp - ss*vrq;
          V[rr2][q] = ss*vrp + cc*vrq;
        }
      }
    }
    double w[3] = {A[0][0], A[1][1], A[2][2]};
    int idx[3] = {0,1,2};
    for (int i=0;i<2;i++) for (int j=0;j<2-i;j++)
      if (w[idx[j]] > w[idx[j+1]]) { int tmp=idx[j]; idx[j]=idx[j+1]; idx[j+1]=tmp; }
    for (int jj=0;jj<3;jj++) for (int ii=0;ii<3;ii++)
      misc[b*12 + jj*3 + ii] = (float)V[jj][idx[ii]];
    misc[b*12+9]=cx; misc[b*12+10]=cy; misc[b*12+11]=cz;
  }
}

// ---------------- build h0 pairs: [F*L][288] = [hX(3) | emb(256) | 0-pad(29)] ----
__global__ void build_h0(const int* __restrict__ seqs, const float* __restrict__ cords,
                         const float* __restrict__ mask, const float* __restrict__ emb,
                         const float* __restrict__ misc,
                         u16* __restrict__ h0h, u16* __restrict__ h0l) {
  int t = threadIdx.x;
  int r = blockIdx.x*4 + (t >> 6);
  int lane = t & 63;
  int f = r >> 9, l = r & 511;
  int b = f >> 3, o = f & 7;
  u16* rh = h0h + (size_t)r * 288;
  u16* rl = h0l + (size_t)r * 288;
  if (lane == 0) {
    float m = mask[b*512 + l];
    const float* X = cords + ((size_t)(b*512 + l)*4 + 1)*3;
    const float* mb = misc + b*12;
    float x = X[0]-mb[9]*m, y = X[1]-mb[10]*m, z = X[2]-mb[11]*m;
    #pragma unroll
    for (int i=0;i<3;i++) {
      float sgn = ((o >> (2-i)) & 1) ? 1.f : -1.f;
      float val = sgn * (mb[0+i]*x + mb[3+i]*y + mb[6+i]*z);
      u16 h,lo; split2(val,h,lo); rh[i]=h; rl[i]=lo;
    }
  }
  if (lane < 29) { rh[259+lane] = 0; rl[259+lane] = 0; }
  int s = seqs[b*512 + l];
  if (s < 0) s = 82;
  const float4 e4 = *((const float4*)(emb + (size_t)s*256) + lane);
  float ev[4] = {e4.x, e4.y, e4.z, e4.w};
  #pragma unroll
  for (int i=0;i<4;i++) {
    u16 h,lo; split2(ev[i],h,lo);
    rh[3 + lane*4 + i] = h; rl[3 + lane*4 + i] = lo;
  }
}

// ---------------- weight prep: wq/wk/wv transpose + split in ONE dispatch ------
__global__ void prep_w3(const float* __restrict__ Wq, const float* __restrict__ Wk,
                        const float* __restrict__ Wv,
                        u16* __restrict__ qTh, u16* __restrict__ qTl,
                        u16* __restrict__ kTh, u16* __restrict__ kTl,
                        u16* __restrict__ vTh, u16* __restrict__ vTl,
                        int Kq, int KPq) {
  int y = blockIdx.y;
  int n = blockIdx.x;           // 0..127 (output row)
  const float* W = (y==0) ? Wq : (y==1) ? Wk : Wv;
  u16* Th = (y==0) ? qTh : (y==1) ? kTh : vTh;
  u16* Tl = (y==0) ? qTl : (y==1) ? kTl : vTl;
  const int K  = (y==0) ? Kq  : 128;
  const int KP = (y==0) ? KPq : 128;
  for (int k = threadIdx.x; k < KP; k += 128) {
    float x = (k < K) ? W[(size_t)k*128 + n] : 0.f;
    u16 h,l; split2(x,h,l);
    Th[(size_t)n*KP + k] = h; Tl[(size_t)n*KP + k] = l;
  }
}

// wuT[(dir*512 + d*4+g)][k] = Wu[k][(dir*4+g)*128 + d]; gates 1,2 pre-scaled by log2(e)
__global__ void prep_wu(const float* __restrict__ Wu, u16* __restrict__ Th, u16* __restrict__ Tl) {
  int n = blockIdx.x;    // 0..511
  int dir = blockIdx.y;  // 0..1
  int k = threadIdx.x;   // 0..127
  int d = n >> 2, g = n & 3;
  float x = Wu[(size_t)k*1024 + (dir*4+g)*128 + d];
  if (g == 1 || g == 2) x *= LOG2E_;
  u16 h,l; split2(x,h,l);
  size_t o = ((size_t)dir*512 + n)*128 + k;
  Th[o]=h; Tl[o]=l;
}

// ---------------- split-bf16 MFMA GEMM ----------------
// EPI: 0 = split pairs; 1 = V^T pairs; 2 = qkT fp32 scale+mask; 3 = pv + residual
//      -> pairs; 4 = fp32 out via row-split triple (Cf / CfB / CfC).
template<int EPI>
__global__ __launch_bounds__(256) void gemm_bb(
    const u16* __restrict__ Ah, const u16* __restrict__ Al,
    const u16* __restrict__ Bh, const u16* __restrict__ Bl,
    int KP, int lda, int ldb,
    long aBatch, long bBatch, long cBatch,
    u16* __restrict__ Ch, u16* __restrict__ Cl, int ldc,
    float* __restrict__ Cf, float* __restrict__ CfB, float* __restrict__ CfC,
    const u16* __restrict__ rh, const u16* __restrict__ rl,
    const float* __restrict__ maskp, float scale)
{
  __shared__ u16 As[2][128][40];
  __shared__ u16 Bs[2][128][40];
  const int t = threadIdx.x;
  const int z = blockIdx.z;
  const int bm = blockIdx.x * 128, bn = blockIdx.y * 128;
  Ah += (size_t)z * aBatch; Al += (size_t)z * aBatch;
  Bh += (size_t)z * bBatch; Bl += (size_t)z * bBatch;

  const int lane = t & 63;
  const int w = t >> 6, wr = w >> 1, wc = w & 1;
  const int fr = lane & 15, g = lane >> 4;

  f32x4 acc[4][4] = {};

  for (int k0 = 0; k0 < KP; k0 += 32) {
    #pragma unroll
    for (int cc = 0; cc < 2; cc++) {
      int c = t + cc*256;
      int m = c >> 2, sub = c & 3;
      const size_t ga = (size_t)(bm + m)*lda + k0 + sub*8;
      const size_t gb = (size_t)(bn + m)*ldb + k0 + sub*8;
      *(int4*)&As[0][m][sub*8] = *(const int4*)(Ah + ga);
      *(int4*)&As[1][m][sub*8] = *(const int4*)(Al + ga);
      *(int4*)&Bs[0][m][sub*8] = *(const int4*)(Bh + gb);
      *(int4*)&Bs[1][m][sub*8] = *(const int4*)(Bl + gb);
    }
    __syncthreads();
    s16x8 af[4][2], bfr[4][2];
    #pragma unroll
    for (int i = 0; i < 4; i++) {
      af[i][0]  = *(const s16x8*)&As[0][wr*64 + i*16 + fr][g*8];
      af[i][1]  = *(const s16x8*)&As[1][wr*64 + i*16 + fr][g*8];
      bfr[i][0] = *(const s16x8*)&Bs[0][wc*64 + i*16 + fr][g*8];
      bfr[i][1] = *(const s16x8*)&Bs[1][wc*64 + i*16 + fr][g*8];
    }
    #pragma unroll
    for (int mi = 0; mi < 4; mi++)
      #pragma unroll
      for (int nj = 0; nj < 4; nj++)
        acc[mi][nj] = __builtin_amdgcn_mfma_f32_16x16x32_bf16(af[mi][0], bfr[nj][0], acc[mi][nj], 0,0,0);
    #pragma unroll
    for (int mi = 0; mi < 4; mi++)
      #pragma unroll
      for (int nj = 0; nj < 4; nj++)
        acc[mi][nj] = __builtin_amdgcn_mfma_f32_16x16x32_bf16(af[mi][0], bfr[nj][1], acc[mi][nj], 0,0,0);
    #pragma unroll
    for (int mi = 0; mi < 4; mi++)
      #pragma unroll
      for (int nj = 0; nj < 4; nj++)
        acc[mi][nj] = __builtin_amdgcn_mfma_f32_16x16x32_bf16(af[mi][1], bfr[nj][0], acc[mi][nj], 0,0,0);
    __syncthreads();
  }

  const int rbase = bm + wr*64, nbase = bn + wc*64;
  #pragma unroll
  for (int mi = 0; mi < 4; mi++) {
    #pragma unroll
    for (int nj = 0; nj < 4; nj++) {
      #pragma unroll
      for (int rg = 0; rg < 4; rg++) {
        int r = rbase + mi*16 + g*4 + rg;
        int n = nbase + nj*16 + fr;
        float val = acc[mi][nj][rg];
        if (EPI == 0) {
          size_t o = (size_t)r*ldc + n;
          u16 h,l; split2(val,h,l);
          Ch[o]=h; Cl[o]=l;
        } else if (EPI == 1) {      // V^T pairs: [frame][n][l]
          size_t o = ((size_t)(r >> 9)*128 + n)*512 + (r & 511);
          u16 h,l; split2(val,h,l);
          Ch[o]=h; Cl[o]=l;
        } else if (EPI == 2) {      // qkT -> fp32 S with scale+mask
          float vv = val * scale;
          if (maskp[(z>>3)*512 + n] == 0.f) vv = -1e9f;
          Cf[(size_t)z*cBatch + (size_t)r*ldc + n] = vv;
        } else if (EPI == 3) {      // pv: + q residual -> pairs
          size_t o = (size_t)z*cBatch + (size_t)r*ldc + n;
          float vv = val + (bf_to_f(rh[o]) + bf_to_f(rl[o]));
          u16 h,l; split2(vv,h,l);
          Ch[o]=h; Cl[o]=l;
        } else {                    // 4: fp32 out, row-split triple
          float* Up;
          if (r < RSPLIT_A)      Up = Cf  + (size_t)r*512;
          else if (r < RSPLIT_B) Up = CfB + (size_t)(r - RSPLIT_A)*512;
          else                   Up = CfC + (size_t)(r - RSPLIT_B)*512;
          Up[n] = val;
        }
      }
    }
  }
}

// ---------------- row softmax over 512, fp32 in -> split-bf16 pairs in place ----
__global__ void softmax_split(float* __restrict__ S) {
  size_t row = blockIdx.x;
  float* p = S + row*512;
  u16* ph = (u16*)p;        // hi plane: first 1024B of row
  u16* pl = ph + 512;       // lo plane: second 1024B
  int t = threadIdx.x; // 64
  float v[8];
  float mx = -1e30f;
  #pragma unroll
  for (int i=0;i<8;i++) { v[i] = p[t + i*64]; mx = fmaxf(mx, v[i]); }
  #pragma unroll
  for (int off=32; off>0; off>>=1) mx = fmaxf(mx, __shfl_xor(mx, off));
  float sum = 0.f;
  #pragma unroll
  for (int i=0;i<8;i++) { v[i] = __expf(v[i]-mx); sum += v[i]; }
  #pragma unroll
  for (int off=32; off>0; off>>=1) sum += __shfl_xor(sum, off);
  float invs = 1.f/sum;
  #pragma unroll
  for (int i=0;i<8;i++) {
    float x = v[i]*invs;
    u16 h,l; split2(x,h,l);
    ph[t + i*64] = h; pl[t + i*64] = l;
  }
}

// ---------------- SRU scan: dir-merged, branch-free register pipeline ----------
// grid (128, ydirs): blockIdx.x = (frame<<1)|half, dir = dirArg + blockIdx.y.
// Internals identical to the best-measured (round-6) version. Per-dir U' is a
// frame-aligned region triple (ua/ub/uc): frames 0..35 / 36..51 / 52..63.
#define CH_ 8
#define LOADC(buf, ch) do { \
  int _c = (ch); \
  _Pragma("unroll") \
  for (int s = 0; s < CH_; s++) { \
    int l = (_c*CH_ + s) ^ lxor; \
    buf[s] = *(const float4*)(Ubase + (size_t)l*512); \
  } \
  __builtin_amdgcn_sched_barrier(0); \
} while(0)

#define COMPC(buf, ch) do { \
  int _c = (ch); \
  float mk[CH_]; \
  _Pragma("unroll") \
  for (int s = 0; s < CH_; s++) { \
    int l = (_c*CH_ + s) ^ lxor; \
    mk[s] = msk[l]; \
  } \
  unsigned pk[CH_]; \
  _Pragma("unroll") \
  for (int s = 0; s < CH_; s++) { \
    float4 u = buf[s]; \
    float xf = (u.y + bfd) + vfd*cstate; \
    float xr = (u.z + brd) + vrd*cstate; \
    float fg = 1.f/(1.f + exp2_fast(-xf)); \
    float rg = 1.f/(1.f + exp2_fast(-xr)); \
    float cn = fg*(cstate - u.x) + u.x; \
    if (mk[s] == 0.f) cn = cstate; \
    float h = (mk[s] == 0.f) ? 0.f : (rg*(cn - u.w) + u.w); \
    cstate = cn; \
    u16 sh_, sl_; split2(h, sh_, sl_); \
    pk[s] = (unsigned)sh_ | ((unsigned)sl_ << 16); \
  } \
  __builtin_amdgcn_sched_barrier(0); \
  _Pragma("unroll") \
  for (int s = 0; s < CH_; s++) { \
    int l = (_c*CH_ + s) ^ lxor; \
    hpph[(size_t)l*256] = (u16)pk[s]; \
    hppl[(size_t)l*256] = (u16)(pk[s] >> 16); \
  } \
  __builtin_amdgcn_sched_barrier(0); \
} while(0)

__global__ __launch_bounds__(64, 1) void sru_scan(
                          const float* __restrict__ ua0, const float* __restrict__ ub0,
                          const float* __restrict__ uc0,
                          const float* __restrict__ ua1, const float* __restrict__ ub1,
                          const float* __restrict__ uc1,
                          const float* __restrict__ mask,
                          const float* __restrict__ vf, const float* __restrict__ vr,
                          const float* __restrict__ bf, const float* __restrict__ br,
                          u16* __restrict__ hph, u16* __restrict__ hpl,
                          int dirArg) {
  const int blk = blockIdx.x;   // 0..127
  const int f = blk >> 1;       // frame
  const int hh = blk & 1;       // channel half
  const int dir = dirArg + blockIdx.y;
  const int t = threadIdx.x;    // 0..63
  const int b = f >> 3;
  __shared__ float msk[512];
  for (int i = t; i < 512; i += 64) msk[i] = mask[b*512 + i];
  __syncthreads();
  const int lxor = dir ? 511 : 0;         // l = step ^ lxor
  const int d = hh*64 + t;                // channel within direction
  const float vfd = vf[dir*128 + d]*LOG2E_, vrd = vr[dir*128 + d]*LOG2E_;
  const float bfd = bf[dir*128 + d]*LOG2E_, brd = br[dir*128 + d]*LOG2E_;
  const size_t fbase = (size_t)f * 512;
  const float* ua = dir ? ua1 : ua0;
  const float* ub = dir ? ub1 : ub0;
  const float* uc = dir ? uc1 : uc0;
  const float* Uf;
  if (f < 36)      Uf = ua + (size_t)f*(512*512);
  else if (f < 52) Uf = ub + (size_t)(f-36)*(512*512);
  else             Uf = uc + (size_t)(f-52)*(512*512);
  const float* Ubase = Uf + d*4;
  u16* hpph = hph + fbase*256 + (size_t)dir*128 + d;
  u16* hppl = hpl + fbase*256 + (size_t)dir*128 + d;

  float4 b0[CH_], b1[CH_], b2[CH_], b3[CH_];
  LOADC(b0, 0); LOADC(b1, 1);
  float cstate = 0.f;
  #pragma unroll 1
  for (int q4 = 0; q4 < 15; q4++) {
    const int base = q4*4;
    LOADC(b2, base+2);
    COMPC(b0, base);
    LOADC(b3, base+3);
    COMPC(b1, base+1);
    LOADC(b0, base+4);
    COMPC(b2, base+2);
    LOADC(b1, base+5);
    COMPC(b3, base+3);
  }
  LOADC(b2, 62);
  COMPC(b0, 60);
  LOADC(b3, 63);
  COMPC(b1, 61);
  COMPC(b2, 62);
  COMPC(b3, 63);
}

// ---------------- mean over 8 sign-frames (reads h pairs) ----------------
__global__ void mean_kernel(const u16* __restrict__ hph, const u16* __restrict__ hpl,
                            float* __restrict__ out) {
  int i = blockIdx.x*256 + threadIdx.x;   // 0..131071, 8 channels each
  int row = i >> 5;        // b*512 + l
  int c8  = i & 31;
  int b = row >> 9, l = row & 511;
  float acc[8] = {};
  #pragma unroll
  for (int o=0;o<8;o++) {
    size_t off = ((size_t)((b*8+o)*512 + l))*256 + c8*8;
    union { int4 v; u16 s[8]; } hv, lv;
    hv.v = *(const int4*)(hph + off);
    lv.v = *(const int4*)(hpl + off);
    #pragma unroll
    for (int j=0;j<8;j++)
      acc[j] += bf_to_f(hv.s[j]) + bf_to_f(lv.s[j]);
  }
  float4 q0, q1;
  q0.x=acc[0]*0.125f; q0.y=acc[1]*0.125f; q0.z=acc[2]*0.125f; q0.w=acc[3]*0.125f;
  q1.x=acc[4]*0.125f; q1.y=acc[5]*0.125f; q1.z=acc[6]*0.125f; q1.w=acc[7]*0.125f;
  float* op = out + (size_t)row*256 + c8*8;
  *(float4*)op = q0;
  *(float4*)(op+4) = q1;
}

extern "C" void kernel_launch(void* const* d_in, const int* in_sizes, int n_in,
                              void* d_out, int out_size, void* d_ws, size_t ws_size,
                              hipStream_t stream) {
  const int*   seqs  = (const int*)d_in[0];
  const float* cords = (const float*)d_in[1];
  const float* mask  = (const float*)d_in[2];
  const float* emb   = (const float*)d_in[3];
  const float* Wq[2] = {(const float*)d_in[4],  (const float*)d_in[12]};
  const float* Wk[2] = {(const float*)d_in[5],  (const float*)d_in[13]};
  const float* Wv[2] = {(const float*)d_in[6],  (const float*)d_in[14]};
  const float* Wu[2] = {(const float*)d_in[7],  (const float*)d_in[15]};
  const float* vf[2] = {(const float*)d_in[8],  (const float*)d_in[16]};
  const float* vr[2] = {(const float*)d_in[9],  (const float*)d_in[17]};
  const float* bfp[2]= {(const float*)d_in[10], (const float*)d_in[18]};
  const float* brp[2]= {(const float*)d_in[11], (const float*)d_in[19]};

  const size_t H0_B = 2*(size_t)M_*288*2;   // 37,748,736
  const size_t Q_B  = 2*(size_t)M_*128*2;   // 16,777,216
  const size_t S_B  = (size_t)M_*512*4;     // 67,108,864
  const size_t HP_B = 2*(size_t)M_*256*2;   // 33,554,432
  const size_t W_B  = (2*128*288 + 4*128*128 + 2*1024*128)*2;  // ~0.8MB

  // merged layout: [misc 4K][h0p][q][k/a][vT][S=U'0][hp][w]
  const size_t NEED_MERGED = 4096 + H0_B + 3*Q_B + S_B + HP_B + W_B;
  const bool merged = (ws_size >= NEED_MERGED);

  char* base = (char*)d_ws;
  float* misc = (float*)base;
  u16* h0p_h = (u16*)(base + 4096);
  u16* h0p_l = h0p_h + (size_t)M_*288;
  u16* q_h   = (u16*)(base + 4096 + H0_B);
  u16* q_l   = q_h + (size_t)M_*128;
  u16* k_h   = (u16*)(base + 4096 + H0_B + Q_B);
  u16* k_l   = k_h + (size_t)M_*128;
  u16* a_h = k_h;  u16* a_l = k_l;     // overlay (k dead after qkT)

  u16 *vT_h, *vT_l;
  float *S, *hp_end_w;
  u16 *hp_h, *hp_l;
  float *U1A, *U1B, *U1C;
  if (merged) {
    vT_h = (u16*)(base + 4096 + H0_B + 2*Q_B);
    vT_l = vT_h + (size_t)M_*128;
    S    = (float*)(base + 4096 + H0_B + 3*Q_B);
    hp_h = (u16*)((char*)S + S_B);
    hp_l = hp_h + (size_t)M_*256;
    hp_end_w = (float*)((char*)hp_h + HP_B);
    U1A = (float*)h0p_h;               // rows 0..18431   (36.0 MB, dead after q GEMM)
    U1B = (float*)q_h;                 // rows 18432..26623 (16 MB, dead after pv)
    U1C = (float*)vT_h;                // rows 26624..32767 (12 MB of 16, dead after pv)
  } else {
    // fallback = round-6 layout: vT overlays hp, U'1 -> S triple (sequential)
    S    = (float*)(base + 4096 + H0_B + 2*Q_B);
    hp_h = (u16*)((char*)S + S_B);
    hp_l = hp_h + (size_t)M_*256;
    vT_h = hp_h; vT_l = hp_l;
    hp_end_w = (float*)((char*)hp_h + HP_B);
    U1A = S; U1B = S + (size_t)RSPLIT_A*512; U1C = S + (size_t)RSPLIT_B*512;
  }
  float* U0A = S;
  float* U0B = S + (size_t)RSPLIT_A*512;
  float* U0C = S + (size_t)RSPLIT_B*512;

  u16* wqT_h = (u16*)hp_end_w;
  u16* wqT_l = wqT_h + 128*288;
  u16* wkT_h = wqT_l + 128*288;
  u16* wkT_l = wkT_h + 128*128;
  u16* wvT_h = wkT_l + 128*128;
  u16* wvT_l = wvT_h + 128*128;
  u16* wuT_h = wvT_l + 128*128;
  u16* wuT_l = wuT_h + 1024*128;

  geom_kernel<<<8, 256, 0, stream>>>(cords, mask, misc);
  build_h0<<<M_/4, 256, 0, stream>>>(seqs, cords, mask, emb, misc, h0p_h, h0p_l);

  const float scale = 0.08838834764831845f; // 1/sqrt(128)
  for (int layer = 0; layer < 2; ++layer) {
    const u16* Ah_in = layer ? hp_h : h0p_h;
    const u16* Al_in = layer ? hp_l : h0p_l;
    const int  Kq    = layer ? 256 : 259;
    const int  KPq   = layer ? 256 : 288;

    prep_w3<<<dim3(128,3), 128, 0, stream>>>(Wq[layer], Wk[layer], Wv[layer],
        wqT_h, wqT_l, wkT_h, wkT_l, wvT_h, wvT_l, Kq, KPq);
    prep_wu<<<dim3(512,2), 128, 0, stream>>>(Wu[layer], wuT_h, wuT_l);

    // q = hin @ Wq -> pairs
    gemm_bb<0><<<dim3(256,1,1), 256, 0, stream>>>(Ah_in, Al_in, wqT_h, wqT_l,
        KPq, KPq, KPq, 0,0,0, q_h, q_l, 128, nullptr,nullptr,nullptr, nullptr,nullptr, nullptr, 0.f);
    // k = q @ Wk -> pairs
    gemm_bb<0><<<dim3(256,1,1), 256, 0, stream>>>(q_h, q_l, wkT_h, wkT_l,
        128, 128, 128, 0,0,0, k_h, k_l, 128, nullptr,nullptr,nullptr, nullptr,nullptr, nullptr, 0.f);
    // v = q @ Wv -> V^T pairs
    gemm_bb<1><<<dim3(256,1,1), 256, 0, stream>>>(q_h, q_l, wvT_h, wvT_l,
        128, 128, 128, 0,0,0, vT_h, vT_l, 0, nullptr,nullptr,nullptr, nullptr,nullptr, nullptr, 0.f);
    // S = q k^T * scale (masked)
    gemm_bb<2><<<dim3(4,4,64), 256, 0, stream>>>(q_h, q_l, k_h, k_l,
        128, 128, 128, 512*128, 512*128, 512*512, nullptr,nullptr, 512, S,nullptr,nullptr,
        nullptr,nullptr, mask, scale);
    // P = softmax(S) -> pairs (in place)
    softmax_split<<<M_, 64, 0, stream>>>(S);
    // a = P @ v + q -> pairs
    gemm_bb<3><<<dim3(4,1,64), 256, 0, stream>>>((const u16*)S, (const u16*)S + 512, vT_h, vT_l,
        512, 1024, 512, 512*1024, 128*512, 512*128, a_h, a_l, 128, nullptr,nullptr,nullptr,
        q_h, q_l, nullptr, 0.f);

    // U' GEMMs + scans
    gemm_bb<4><<<dim3(256,4,1), 256, 0, stream>>>(a_h, a_l,
        wuT_h, wuT_l, 128, 128, 128, 0,0,0, nullptr,nullptr, 512,
        U0A, U0B, U0C, nullptr,nullptr, nullptr, 0.f);
    if (merged) {
      gemm_bb<4><<<dim3(256,4,1), 256, 0, stream>>>(a_h, a_l,
          wuT_h + (size_t)512*128, wuT_l + (size_t)512*128, 128, 128, 128, 0,0,0,
          nullptr,nullptr, 512, U1A, U1B, U1C, nullptr,nullptr, nullptr, 0.f);
      sru_scan<<<dim3(128,2), 64, 0, stream>>>(U0A,U0B,U0C, U1A,U1B,U1C, mask,
          vf[layer], vr[layer], bfp[layer], brp[layer], hp_h, hp_l, 0);
    } else {
      sru_scan<<<dim3(128,1), 64, 0, stream>>>(U0A,U0B,U0C, U0A,U0B,U0C, mask,
          vf[layer], vr[layer], bfp[layer], brp[layer], hp_h, hp_l, 0);
      gemm_bb<4><<<dim3(256,4,1), 256, 0, stream>>>(a_h, a_l,
          wuT_h + (size_t)512*128, wuT_l + (size_t)512*128, 128, 128, 128, 0,0,0,
          nullptr,nullptr, 512, U0A, U0B, U0C, nullptr,nullptr, nullptr, 0.f);
      sru_scan<<<dim3(128,1), 64, 0, stream>>>(U0A,U0B,U0C, U0A,U0B,U0C, mask,
          vf[layer], vr[layer], bfp[layer], brp[layer], hp_h, hp_l, 1);
    }
  }
  mean_kernel<<<512, 256, 0, stream>>>(hp_h, hp_l, (float*)d_out);
}